// Round 3
// baseline (1638.097 us; speedup 1.0000x reference)
//
#include <hip/hip_runtime.h>

#define BATCH 4
#define NPTS  4096
#define NC    1024
#define KNN   32
#define CIN   128
#define CO    256
#define DP    136   // padded feature dim (max over types); pad entries are exact zeros

// output layout (flat f32, reference return order)
#define OFF_CXYZ 0
#define OFF_CMAD (BATCH*NC*3)
#define OFF_CADJ (OFF_CMAD + BATCH*NC*3)
#define OFF_CPT  (OFF_CADJ + BATCH*NC*2)
#define OFF_OMAD (OFF_CPT  + BATCH*NC*4)
#define OFF_OADJ (OFF_OMAD + BATCH*NC*CO)
#define OFF_OPT  (OFF_OADJ + BATCH*NC*CO)
#define OFF_OCST (OFF_OPT  + BATCH*NC*CO)

typedef unsigned long long u64;

// ---------------------------------------------------------------------------
// u64 wave-64 reduce via DPP (VALU pipe). Result valid in lane 63.
// ---------------------------------------------------------------------------
template<bool MAXI>
__device__ __forceinline__ u64 wave_red_u64(u64 k)
{
    const int oldv = MAXI ? 0 : -1;
#define DPP_STEP(C)                                                              \
    {                                                                            \
        unsigned plo = (unsigned)__builtin_amdgcn_update_dpp(oldv, (int)(unsigned)k,        C, 0xf, 0xf, false); \
        unsigned phi = (unsigned)__builtin_amdgcn_update_dpp(oldv, (int)(unsigned)(k>>32),  C, 0xf, 0xf, false); \
        u64 p = ((u64)phi << 32) | plo;                                          \
        if (MAXI ? (p > k) : (p < k)) k = p;                                     \
    }
    DPP_STEP(0x111) DPP_STEP(0x112) DPP_STEP(0x114)
    DPP_STEP(0x118) DPP_STEP(0x142) DPP_STEP(0x143)
#undef DPP_STEP
    return k;
}

// ---------------------------------------------------------------------------
// One FPS distance+local-reduce step for one batch (verified round-2 math,
// bit-identical: strict-> chains keep smallest point index on ties).
// Returns the per-thread u64 key (dist_bits<<32)|~idx for the DPP reduce.
// ---------------------------------------------------------------------------
__device__ __forceinline__ u64 fps_step(const float* px, const float* py, const float* pz,
                                        float* dd, float cx, float cy, float cz, int t)
{
    float    gm[4] = {-1.f, -1.f, -1.f, -1.f};
    unsigned gi[4] = {0u, 0u, 0u, 0u};
#pragma unroll
    for (int i = 0; i < 16; ++i) {
        float dx = __fsub_rn(px[i], cx);
        float dy = __fsub_rn(py[i], cy);
        float dz = __fsub_rn(pz[i], cz);
        float d  = __fadd_rn(__fadd_rn(__fmul_rn(dx,dx), __fmul_rn(dy,dy)), __fmul_rn(dz,dz));
        float nd = fminf(dd[i], d);
        dd[i] = nd;
        const int g = i >> 2;
        if (nd > gm[g]) gi[g] = (unsigned)(t + i*256);
        gm[g] = fmaxf(gm[g], nd);
    }
    bool c1 = gm[1] > gm[0]; float a0 = c1 ? gm[1] : gm[0]; unsigned b0 = c1 ? gi[1] : gi[0];
    bool c3 = gm[3] > gm[2]; float a1 = c3 ? gm[3] : gm[2]; unsigned b1 = c3 ? gi[3] : gi[2];
    bool cf = a1 > a0;       float am = cf ? a1 : a0;       unsigned bm = cf ? b1 : b0;
    return ((u64)__float_as_uint(am) << 32) | (u64)(unsigned)~bm;
}

// ---------------------------------------------------------------------------
// Fused kernel: blocks 0..1 each run FPS for TWO batches interleaved in one
// instruction stream (A's reduce/LDS latency hides under B's distance issue
// and vice versa; the two readback chains overlap each other). Blocks 2..545
// precompute M[type] = Wq·Wk^T (zero-padded) and the zero-padded Wvp.
// ---------------------------------------------------------------------------
__global__ __launch_bounds__(256) void fps_prep_kernel(
    const float* __restrict__ xyz, int* __restrict__ fps_idx,
    const float* __restrict__ wq_mad, const float* __restrict__ wk_mad, const float* __restrict__ wv_mad,
    const float* __restrict__ wq_adj, const float* __restrict__ wk_adj, const float* __restrict__ wv_adj,
    const float* __restrict__ wq_pt,  const float* __restrict__ wk_pt,  const float* __restrict__ wv_pt,
    const float* __restrict__ wq_cst, const float* __restrict__ wk_cst, const float* __restrict__ wv_cst,
    float* __restrict__ M, float* __restrict__ Wvp)
{
    __shared__ float2 s_xy[2][NPTS];        // 64 KB (prep reuses as scratch)
    __shared__ float  s_z [2][NPTS];        // 32 KB
    __shared__ u64    s_ck[2][2][4];        // [batch][buf][wave]
    const int t = threadIdx.x;

    if (blockIdx.x >= 2) {
        // ---------------- prep path ----------------
        const int r    = blockIdx.x - 2;       // 0..4*DP-1
        const int type = r / DP;
        const int row  = r - type * DP;
        const float* wq; const float* wk; const float* wv; int D;
        if (type == 0)      { wq=wq_mad; wk=wk_mad; wv=wv_mad; D=131; }
        else if (type == 1) { wq=wq_adj; wk=wk_adj; wv=wv_adj; D=132; }
        else if (type == 2) { wq=wq_pt;  wk=wk_pt;  wv=wv_pt;  D=136; }
        else                { wq=wq_cst; wk=wk_cst; wv=wv_cst; D=131; }

        // zero-padded Wvp row
        Wvp[((size_t)type*DP + row)*CO + t] = (row < D) ? wv[(size_t)row*CO + t] : 0.f;

        // M[row][d] = sum_h Wq[row][h] * Wk[d][h]   (zero for d >= D)
        if (row < CIN) {
            float* sq = (float*)s_xy;
            sq[t] = wq[(size_t)row*CO + t];
            __syncthreads();
            if (t < DP) {
                float acc = 0.f;
                if (t < D) {
                    const float* wkr = wk + (size_t)t * CO;
                    for (int h = 0; h < CO; h += 4) {
                        float4 a = *(const float4*)&wkr[h];
                        float4 b4 = *(const float4*)&sq[h];
                        acc = fmaf(a.x,b4.x,acc); acc = fmaf(a.y,b4.y,acc);
                        acc = fmaf(a.z,b4.z,acc); acc = fmaf(a.w,b4.w,acc);
                    }
                }
                M[((size_t)type*CIN + row)*DP + t] = acc;
            }
        }
        return;
    }

    // ---------------- FPS path: two batches per block ----------------
    const int b0 = blockIdx.x * 2, b1 = b0 + 1;
    const float* xb0 = xyz + (size_t)b0 * NPTS * 3;
    const float* xb1 = xyz + (size_t)b1 * NPTS * 3;

    float px0[16], py0[16], pz0[16], dd0[16];
    float px1[16], py1[16], pz1[16], dd1[16];
#pragma unroll
    for (int i = 0; i < 16; ++i) {
        int p = t + i * 256;
        px0[i] = xb0[p*3+0]; py0[i] = xb0[p*3+1]; pz0[i] = xb0[p*3+2];
        px1[i] = xb1[p*3+0]; py1[i] = xb1[p*3+1]; pz1[i] = xb1[p*3+2];
        s_xy[0][p] = make_float2(px0[i], py0[i]); s_z[0][p] = pz0[i];
        s_xy[1][p] = make_float2(px1[i], py1[i]); s_z[1][p] = pz1[i];
        dd0[i] = 1e10f; dd1[i] = 1e10f;
    }
    __syncthreads();

    int farA = 0, farB = 0;
    float cxA = xb0[0], cyA = xb0[1], czA = xb0[2];
    float cxB = xb1[0], cyB = xb1[1], czB = xb1[2];

    for (int s = 0; s < NC; ++s) {
        if (t == 0) {
            fps_idx[b0*NC + s] = farA;
            fps_idx[b1*NC + s] = farB;
        }
        const int buf = s & 1;

        // ---- batch A: distances + wave reduce + write partial ----
        u64 kA = fps_step(px0, py0, pz0, dd0, cxA, cyA, czA, t);
        kA = wave_red_u64<true>(kA);
        if ((t & 63) == 63) s_ck[0][buf][t>>6] = kA;

        // ---- batch B: distances + wave reduce + write partial ----
        // (issues while A's DPP/LDS-write latency drains)
        u64 kB = fps_step(px1, py1, pz1, dd1, cxB, cyB, czB, t);
        kB = wave_red_u64<true>(kB);
        if ((t & 63) == 63) s_ck[1][buf][t>>6] = kB;

        __syncthreads();

        // ---- readbacks (A and B independent -> latencies overlap) ----
        u64 a0 = s_ck[0][buf][0], a1 = s_ck[0][buf][1], a2 = s_ck[0][buf][2], a3 = s_ck[0][buf][3];
        u64 e0 = s_ck[1][buf][0], e1 = s_ck[1][buf][1], e2 = s_ck[1][buf][2], e3 = s_ck[1][buf][3];
        if (a1 > a0) a0 = a1;
        if (a3 > a2) a2 = a3;
        if (a2 > a0) a0 = a2;
        if (e1 > e0) e0 = e1;
        if (e3 > e2) e2 = e3;
        if (e2 > e0) e0 = e2;
        farA = (int)~((unsigned)a0);
        farB = (int)~((unsigned)e0);
        float2 ca = s_xy[0][farA]; float za = s_z[0][farA];
        float2 cb = s_xy[1][farB]; float zb = s_z[1][farB];
        cxA = ca.x; cyA = ca.y; czA = za;
        cxB = cb.x; cyB = cb.y; czB = zb;
    }
}

// ---------------------------------------------------------------------------
// kNN with tournament caching (verified): per-thread local min cached in a
// register; per pass only cached minima are DPP-reduced; the winning thread
// clears its key and rescans its 16. Bit-exact vs reference.
// ---------------------------------------------------------------------------
__global__ __launch_bounds__(256) void knn_kernel(const float* __restrict__ xyz,
                                                  const int* __restrict__ fps_idx,
                                                  int* __restrict__ nbr_idx)
{
    const int bs = blockIdx.x;
    const int b  = bs >> 10;
    const int t  = threadIdx.x;
    const float* xb = xyz + (size_t)b * NPTS * 3;
    const int ci = fps_idx[bs];
    const float cx = xb[ci*3], cy = xb[ci*3+1], cz = xb[ci*3+2];
    const float sqc = __fadd_rn(__fadd_rn(__fmul_rn(cx,cx), __fmul_rn(cy,cy)), __fmul_rn(cz,cz));

    u64 key[16];
#pragma unroll
    for (int i = 0; i < 16; ++i) {
        int p = t + i * 256;
        float x = xb[p*3], y = xb[p*3+1], z = xb[p*3+2];
        float sqm = __fadd_rn(__fadd_rn(__fmul_rn(x,x), __fmul_rn(y,y)), __fmul_rn(z,z));
        float dot = __fadd_rn(__fadd_rn(__fmul_rn(cx,x), __fmul_rn(cy,y)), __fmul_rn(cz,z));
        float dv  = __fsub_rn(__fadd_rn(sqc, sqm), __fmul_rn(2.0f, dot));
        unsigned u = __float_as_uint(dv);
        u ^= (unsigned)(((int)u >> 31)) | 0x80000000u;   // order-monotonic for all floats
        key[i] = ((u64)u << 32) | (unsigned)p;
    }
    u64 kmin = key[0];
#pragma unroll
    for (int i = 1; i < 16; ++i) if (key[i] < kmin) kmin = key[i];

    __shared__ u64 s_ck[2][4];

    for (int kk = 0; kk < KNN; ++kk) {
        u64 k = wave_red_u64<false>(kmin);
        const int buf = kk & 1;
        if ((t & 63) == 63) s_ck[buf][t>>6] = k;
        __syncthreads();
        u64 k0 = s_ck[buf][0], k1 = s_ck[buf][1], k2 = s_ck[buf][2], k3 = s_ck[buf][3];
        if (k1 < k0) k0 = k1;
        if (k3 < k2) k2 = k3;
        if (k2 < k0) k0 = k2;
        unsigned w = (unsigned)k0;
        if (t == 0) nbr_idx[bs*KNN + kk] = (int)w;
        if ((w & 255u) == (unsigned)t) {          // only the owner thread
#pragma unroll
            for (int i = 0; i < 16; ++i)
                if (w == (unsigned)(t + i*256)) key[i] = ~0ull;
            u64 m = key[0];
#pragma unroll
            for (int i = 1; i < 16; ++i) if (key[i] < m) m = key[i];
            kmin = m;
        }
    }
}

// ---------------------------------------------------------------------------
// Attention with precomputed M = Wq·Wk^T and padded Wvp. Wave g owns center
// g: staging, u = cf·M, scores, softmax, wfea are all wave-private; only the
// o-phase (o = wf·Wvp, coalesced on h=t) crosses waves. All LDS reads f4.
// ---------------------------------------------------------------------------
template<int TYPE>
__device__ __forceinline__ void attn_t(
    int b, int bs0, int ci,
    const float* __restrict__ fea, const float* __restrict__ aux,
    const float* __restrict__ Mt, const float* __restrict__ Wvpt,
    float* __restrict__ outp,
    float (*s_cf)[CIN], float (*s_u)[DP], float (*s_fea)[KNN][DP],
    float (*s_sc)[KNN], float (*s_wf)[DP], const int (*s_nbr4)[KNN])
{
    const int t = threadIdx.x, g = t >> 6, l = t & 63;
    const int l31 = l & 31, h32 = l >> 5;

    // ---- stage (wave-private to center g) ----
    if (l < 32) {
        float4 v = *(const float4*)&fea[((size_t)(b*NPTS + ci))*CIN + l*4];
        *(float4*)&s_cf[g][l*4] = v;
    }
#pragma unroll
    for (int it = 0; it < 16; ++it) {
        int kk = it*2 + h32;
        int j  = s_nbr4[g][kk];
        float4 v = *(const float4*)&fea[((size_t)(b*NPTS + j))*CIN + l31*4];
        *(float4*)&s_fea[g][kk][l31*4] = v;
    }
    if (l < KNN) {
        int j = s_nbr4[g][l];
        float pad[8];
        if (TYPE == 0 || TYPE == 3) {
#pragma unroll
            for (int i = 0; i < 3; ++i)
                pad[i] = aux[(size_t)(b*NPTS + j)*3 + i] - aux[(size_t)(b*NPTS + ci)*3 + i];
            pad[3]=pad[4]=pad[5]=pad[6]=pad[7]=0.f;
        } else if (TYPE == 1) {
            pad[0] = aux[(size_t)(b*NPTS + j)*2 + 0];
            pad[1] = aux[(size_t)(b*NPTS + j)*2 + 1];
            pad[2] = aux[(size_t)(b*NPTS + ci)*2 + 0];
            pad[3] = aux[(size_t)(b*NPTS + ci)*2 + 1];
            pad[4]=pad[5]=pad[6]=pad[7]=0.f;
        } else {
#pragma unroll
            for (int i = 0; i < 4; ++i) pad[i]   = aux[(size_t)(b*NPTS + j)*4 + i];
#pragma unroll
            for (int i = 0; i < 4; ++i) pad[4+i] = aux[(size_t)(b*NPTS + ci)*4 + i];
        }
#pragma unroll
        for (int i = 0; i < 8; ++i) s_fea[g][l][CIN+i] = pad[i];
    }
    __syncthreads();

    // ---- u[g][d] = sum_c cf[g][c] * M[c][d]  (M coalesced, cf via b128) ----
#pragma unroll
    for (int j = 0; j < 3; ++j) {
        int d = l + 64*j;
        if (d < DP) {
            float acc = 0.f;
            for (int c = 0; c < CIN; c += 4) {
                float4 cf4 = *(const float4*)&s_cf[g][c];
                acc = fmaf(cf4.x, Mt[(size_t)(c+0)*DP + d], acc);
                acc = fmaf(cf4.y, Mt[(size_t)(c+1)*DP + d], acc);
                acc = fmaf(cf4.z, Mt[(size_t)(c+2)*DP + d], acc);
                acc = fmaf(cf4.w, Mt[(size_t)(c+3)*DP + d], acc);
            }
            s_u[g][d] = acc;
        }
    }
    __syncthreads();

    // ---- scores[g][kk] = (u[g] . fea[g][kk]) / 16  (two dots per wave) ----
#pragma unroll
    for (int it = 0; it < 16; ++it) {
        int kk = it*2 + h32;
        float acc = 0.f;
        for (int c = l31; c < DP/4; c += 32) {
            float4 f4 = *(const float4*)&s_fea[g][kk][c*4];
            float4 u4 = *(const float4*)&s_u[g][c*4];
            acc = fmaf(f4.x,u4.x,acc); acc = fmaf(f4.y,u4.y,acc);
            acc = fmaf(f4.z,u4.z,acc); acc = fmaf(f4.w,u4.w,acc);
        }
#pragma unroll
        for (int off = 16; off; off >>= 1) acc += __shfl_xor(acc, off);
        if (l31 == 0) s_sc[g][kk] = acc * 0.0625f;
    }
    __syncthreads();

    // ---- softmax over 32 (lanes 0..31 of wave g) ----
    if (l < KNN) {
        float sc = s_sc[g][l];
        float m = sc;
#pragma unroll
        for (int off = 16; off; off >>= 1) m = fmaxf(m, __shfl_xor(m, off));
        float e = expf(sc - m);
        float ssum = e;
#pragma unroll
        for (int off = 16; off; off >>= 1) ssum += __shfl_xor(ssum, off);
        s_sc[g][l] = e / ssum;
    }
    __syncthreads();

    // ---- wfea[g][d] = sum_k attn[g][k] * fea[g][k][d]  (f4 chunks) ----
    if (l < DP/4) {
        const int d0 = l*4;
        float w0=0.f, w1=0.f, w2=0.f, w3=0.f;
#pragma unroll
        for (int k4 = 0; k4 < KNN; k4 += 4) {
            float4 a  = *(const float4*)&s_sc[g][k4];
            float4 f0 = *(const float4*)&s_fea[g][k4+0][d0];
            float4 f1 = *(const float4*)&s_fea[g][k4+1][d0];
            float4 f2 = *(const float4*)&s_fea[g][k4+2][d0];
            float4 f3 = *(const float4*)&s_fea[g][k4+3][d0];
            w0=fmaf(a.x,f0.x,w0); w1=fmaf(a.x,f0.y,w1); w2=fmaf(a.x,f0.z,w2); w3=fmaf(a.x,f0.w,w3);
            w0=fmaf(a.y,f1.x,w0); w1=fmaf(a.y,f1.y,w1); w2=fmaf(a.y,f1.z,w2); w3=fmaf(a.y,f1.w,w3);
            w0=fmaf(a.z,f2.x,w0); w1=fmaf(a.z,f2.y,w1); w2=fmaf(a.z,f2.z,w2); w3=fmaf(a.z,f2.w,w3);
            w0=fmaf(a.w,f3.x,w0); w1=fmaf(a.w,f3.y,w1); w2=fmaf(a.w,f3.z,w2); w3=fmaf(a.w,f3.w,w3);
        }
        s_wf[g][d0+0]=w0; s_wf[g][d0+1]=w1; s_wf[g][d0+2]=w2; s_wf[g][d0+3]=w3;
    }
    __syncthreads();

    // ---- o[g][h=t] = sum_d wf[g][d] * Wvp[d][h]  (cross-wave, coalesced) ----
    float o0=0.f, o1=0.f, o2=0.f, o3=0.f;
    for (int d4 = 0; d4 < DP/4; ++d4) {
        float4 wf0 = *(const float4*)&s_wf[0][d4*4];
        float4 wf1 = *(const float4*)&s_wf[1][d4*4];
        float4 wf2 = *(const float4*)&s_wf[2][d4*4];
        float4 wf3 = *(const float4*)&s_wf[3][d4*4];
        float v0 = Wvpt[(size_t)(d4*4+0)*CO + t];
        float v1 = Wvpt[(size_t)(d4*4+1)*CO + t];
        float v2 = Wvpt[(size_t)(d4*4+2)*CO + t];
        float v3 = Wvpt[(size_t)(d4*4+3)*CO + t];
        o0=fmaf(wf0.x,v0,o0); o0=fmaf(wf0.y,v1,o0); o0=fmaf(wf0.z,v2,o0); o0=fmaf(wf0.w,v3,o0);
        o1=fmaf(wf1.x,v0,o1); o1=fmaf(wf1.y,v1,o1); o1=fmaf(wf1.z,v2,o1); o1=fmaf(wf1.w,v3,o1);
        o2=fmaf(wf2.x,v0,o2); o2=fmaf(wf2.y,v1,o2); o2=fmaf(wf2.z,v2,o2); o2=fmaf(wf2.w,v3,o2);
        o3=fmaf(wf3.x,v0,o3); o3=fmaf(wf3.y,v1,o3); o3=fmaf(wf3.z,v2,o3); o3=fmaf(wf3.w,v3,o3);
    }
    outp[(size_t)(bs0+0)*CO + t] = o0;
    outp[(size_t)(bs0+1)*CO + t] = o1;
    outp[(size_t)(bs0+2)*CO + t] = o2;
    outp[(size_t)(bs0+3)*CO + t] = o3;
    __syncthreads();
}

__global__ __launch_bounds__(256) void attn_kernel(
    const float* __restrict__ xyz, const float* __restrict__ mad,
    const float* __restrict__ adj, const float* __restrict__ pt,
    const float* __restrict__ mad_fea, const float* __restrict__ adj_fea,
    const float* __restrict__ pt_fea,  const float* __restrict__ cst_fea,
    const float* __restrict__ M, const float* __restrict__ Wvp,
    const int* __restrict__ fps_idx, const int* __restrict__ nbr_idx,
    float* __restrict__ out)
{
    __shared__ float s_cf[4][CIN];
    __shared__ float s_u[4][DP];
    __shared__ float s_fea[4][KNN][DP];
    __shared__ float s_sc[4][KNN];
    __shared__ float s_wf[4][DP];
    __shared__ int   s_nbr4[4][KNN];
    __shared__ int   s_ci4[4];

    const int bs0 = blockIdx.x * 4;
    const int b   = bs0 >> 10;
    const int t   = threadIdx.x;
    const int g   = t >> 6, l = t & 63;

    if (t < 4) s_ci4[t] = fps_idx[bs0 + t];
    if (t < 128) s_nbr4[t>>5][t&31] = nbr_idx[(bs0 + (t>>5))*KNN + (t&31)];
    __syncthreads();
    const int ci = s_ci4[g];

    // small per-center outputs (wave-private)
    if (l < 3)             out[OFF_CXYZ + (bs0+g)*3 + l]      = xyz[(size_t)(b*NPTS+ci)*3 + l];
    if (l >= 4 && l < 7)   out[OFF_CMAD + (bs0+g)*3 + (l-4)]  = mad[(size_t)(b*NPTS+ci)*3 + (l-4)];
    if (l >= 8 && l < 10)  out[OFF_CADJ + (bs0+g)*2 + (l-8)]  = adj[(size_t)(b*NPTS+ci)*2 + (l-8)];
    if (l >= 12 && l < 16) out[OFF_CPT  + (bs0+g)*4 + (l-12)] = pt[(size_t)(b*NPTS+ci)*4 + (l-12)];

    attn_t<0>(b, bs0, ci, mad_fea, mad, M + 0*CIN*DP, Wvp + 0*DP*CO, out + OFF_OMAD,
              s_cf, s_u, s_fea, s_sc, s_wf, s_nbr4);
    attn_t<1>(b, bs0, ci, adj_fea, adj, M + 1*CIN*DP, Wvp + 1*DP*CO, out + OFF_OADJ,
              s_cf, s_u, s_fea, s_sc, s_wf, s_nbr4);
    attn_t<2>(b, bs0, ci, pt_fea,  pt,  M + 2*CIN*DP, Wvp + 2*DP*CO, out + OFF_OPT,
              s_cf, s_u, s_fea, s_sc, s_wf, s_nbr4);
    attn_t<3>(b, bs0, ci, cst_fea, xyz, M + 3*CIN*DP, Wvp + 3*DP*CO, out + OFF_OCST,
              s_cf, s_u, s_fea, s_sc, s_wf, s_nbr4);
}

extern "C" void kernel_launch(void* const* d_in, const int* in_sizes, int n_in,
                              void* d_out, int out_size, void* d_ws, size_t ws_size,
                              hipStream_t stream)
{
    const float* xyz     = (const float*)d_in[0];
    const float* mad     = (const float*)d_in[1];
    const float* adj     = (const float*)d_in[2];
    const float* pt      = (const float*)d_in[3];
    const float* mad_fea = (const float*)d_in[4];
    const float* adj_fea = (const float*)d_in[5];
    const float* pt_fea  = (const float*)d_in[6];
    const float* cst_fea = (const float*)d_in[7];
    const float* wq_mad  = (const float*)d_in[8];
    const float* wk_mad  = (const float*)d_in[9];
    const float* wv_mad  = (const float*)d_in[10];
    const float* wq_adj  = (const float*)d_in[11];
    const float* wk_adj  = (const float*)d_in[12];
    const float* wv_adj  = (const float*)d_in[13];
    const float* wq_pt   = (const float*)d_in[14];
    const float* wk_pt   = (const float*)d_in[15];
    const float* wv_pt   = (const float*)d_in[16];
    const float* wq_cst  = (const float*)d_in[17];
    const float* wk_cst  = (const float*)d_in[18];
    const float* wv_cst  = (const float*)d_in[19];
    float* out = (float*)d_out;

    int*   fps_idx = (int*)d_ws;                      // 4096 ints
    int*   nbr_idx = fps_idx + BATCH*NC;              // 131072 ints
    float* M       = (float*)(nbr_idx + BATCH*NC*KNN);// 4*128*136 floats
    float* Wvp     = M + 4*CIN*DP;                    // 4*136*256 floats

    fps_prep_kernel<<<2 + 4*DP, 256, 0, stream>>>(xyz, fps_idx,
        wq_mad, wk_mad, wv_mad, wq_adj, wk_adj, wv_adj,
        wq_pt, wk_pt, wv_pt, wq_cst, wk_cst, wv_cst, M, Wvp);
    knn_kernel<<<BATCH*NC, 256, 0, stream>>>(xyz, fps_idx, nbr_idx);
    attn_kernel<<<BATCH*NC/4, 256, 0, stream>>>(xyz, mad, adj, pt,
        mad_fea, adj_fea, pt_fea, cst_fea, M, Wvp, fps_idx, nbr_idx, out);
}

// Round 4
// 1471.141 us; speedup vs baseline: 1.1135x; 1.1135x over previous
//
#include <hip/hip_runtime.h>

#define BATCH 4
#define NPTS  4096
#define NC    1024
#define KNN   32
#define CIN   128
#define CO    256
#define DP    136   // padded feature dim (max over types); pad entries are exact zeros

// output layout (flat f32, reference return order)
#define OFF_CXYZ 0
#define OFF_CMAD (BATCH*NC*3)
#define OFF_CADJ (OFF_CMAD + BATCH*NC*3)
#define OFF_CPT  (OFF_CADJ + BATCH*NC*2)
#define OFF_OMAD (OFF_CPT  + BATCH*NC*4)
#define OFF_OADJ (OFF_OMAD + BATCH*NC*CO)
#define OFF_OPT  (OFF_OADJ + BATCH*NC*CO)
#define OFF_OCST (OFF_OPT  + BATCH*NC*CO)

typedef unsigned long long u64;

// ---------------------------------------------------------------------------
// u64 wave-64 reduce via DPP (VALU pipe). Result valid in lane 63.
// ---------------------------------------------------------------------------
template<bool MAXI>
__device__ __forceinline__ u64 wave_red_u64(u64 k)
{
    const int oldv = MAXI ? 0 : -1;
#define DPP_STEP(C)                                                              \
    {                                                                            \
        unsigned plo = (unsigned)__builtin_amdgcn_update_dpp(oldv, (int)(unsigned)k,        C, 0xf, 0xf, false); \
        unsigned phi = (unsigned)__builtin_amdgcn_update_dpp(oldv, (int)(unsigned)(k>>32),  C, 0xf, 0xf, false); \
        u64 p = ((u64)phi << 32) | plo;                                          \
        if (MAXI ? (p > k) : (p < k)) k = p;                                     \
    }
    DPP_STEP(0x111) DPP_STEP(0x112) DPP_STEP(0x114)
    DPP_STEP(0x118) DPP_STEP(0x142) DPP_STEP(0x143)
#undef DPP_STEP
    return k;
}

// ---------------------------------------------------------------------------
// Fused kernel, 1024 threads/block.
// Blocks 0..3: FPS, one batch each, 16 waves (4/SIMD) so the per-step serial
// chain (DPP reduce -> LDS -> barrier -> readback -> coord fetch) of one wave
// hides under the distance issue of the other 3 waves on the same SIMD.
// Blocks 4..547: prep (M = Wq·Wk^T zero-padded, Wvp zero-padded), gated to
// t<256, riding on the CUs idle during FPS.
// ---------------------------------------------------------------------------
__global__ __launch_bounds__(1024) void fps_prep_kernel(
    const float* __restrict__ xyz, int* __restrict__ fps_idx,
    const float* __restrict__ wq_mad, const float* __restrict__ wk_mad, const float* __restrict__ wv_mad,
    const float* __restrict__ wq_adj, const float* __restrict__ wk_adj, const float* __restrict__ wv_adj,
    const float* __restrict__ wq_pt,  const float* __restrict__ wk_pt,  const float* __restrict__ wv_pt,
    const float* __restrict__ wq_cst, const float* __restrict__ wk_cst, const float* __restrict__ wv_cst,
    float* __restrict__ M, float* __restrict__ Wvp)
{
    __shared__ float4 s_xyz[NPTS];          // 64 KB (prep reuses as scratch)
    __shared__ u64    s_ck[2][16];
    const int t = threadIdx.x;

    if (blockIdx.x >= BATCH) {
        // ---------------- prep path (t < 256 active; barriers all-thread) ----
        const int r    = blockIdx.x - BATCH;   // 0..4*DP-1
        const int type = r / DP;
        const int row  = r - type * DP;
        const float* wq; const float* wk; const float* wv; int D;
        if (type == 0)      { wq=wq_mad; wk=wk_mad; wv=wv_mad; D=131; }
        else if (type == 1) { wq=wq_adj; wk=wk_adj; wv=wv_adj; D=132; }
        else if (type == 2) { wq=wq_pt;  wk=wk_pt;  wv=wv_pt;  D=136; }
        else                { wq=wq_cst; wk=wk_cst; wv=wv_cst; D=131; }

        // zero-padded Wvp row
        if (t < 256)
            Wvp[((size_t)type*DP + row)*CO + t] = (row < D) ? wv[(size_t)row*CO + t] : 0.f;

        // M[row][d] = sum_h Wq[row][h] * Wk[d][h]   (zero for d >= D)
        if (row < CIN) {
            float* sq = (float*)s_xyz;
            if (t < 256) sq[t] = wq[(size_t)row*CO + t];
            __syncthreads();
            if (t < DP) {
                float acc = 0.f;
                if (t < D) {
                    const float* wkr = wk + (size_t)t * CO;
                    for (int h = 0; h < CO; h += 4) {
                        float4 a = *(const float4*)&wkr[h];
                        float4 b4 = *(const float4*)&sq[h];
                        acc = fmaf(a.x,b4.x,acc); acc = fmaf(a.y,b4.y,acc);
                        acc = fmaf(a.z,b4.z,acc); acc = fmaf(a.w,b4.w,acc);
                    }
                }
                M[((size_t)type*CIN + row)*DP + t] = acc;
            }
        }
        return;
    }

    // ---------------- FPS path: 1024 threads, 4 points/thread ----------------
    const int b = blockIdx.x;
    const float* xb = xyz + (size_t)b * NPTS * 3;

    float px[4], py[4], pz[4], dd[4];
#pragma unroll
    for (int i = 0; i < 4; ++i) {
        int p = t + i * 1024;
        px[i] = xb[p*3+0]; py[i] = xb[p*3+1]; pz[i] = xb[p*3+2];
        s_xyz[p] = make_float4(px[i], py[i], pz[i], 0.f);
        dd[i] = 1e10f;
    }
    __syncthreads();

    int far = 0;
    float cx = xb[0], cy = xb[1], cz = xb[2];
    for (int s = 0; s < NC; ++s) {
        if (t == 0) fps_idx[b*NC + s] = far;

        // single running-max chain over 4 points; strict > keeps the
        // EARLIEST i -> smallest point index on ties (reference semantics)
        float    am = -1.f;
        unsigned bm = 0u;
#pragma unroll
        for (int i = 0; i < 4; ++i) {
            float dx = __fsub_rn(px[i], cx);
            float dy = __fsub_rn(py[i], cy);
            float dz = __fsub_rn(pz[i], cz);
            float d  = __fadd_rn(__fadd_rn(__fmul_rn(dx,dx), __fmul_rn(dy,dy)), __fmul_rn(dz,dz));
            float nd = fminf(dd[i], d);
            dd[i] = nd;
            if (nd > am) bm = (unsigned)(t + i*1024);
            am = fmaxf(am, nd);
        }
        // same key as the verified tournament: (dist_bits<<32) | ~idx
        u64 k = ((u64)__float_as_uint(am) << 32) | (u64)(unsigned)~bm;

        k = wave_red_u64<true>(k);

        const int buf = s & 1;
        if ((t & 63) == 63) s_ck[buf][t>>6] = k;
        __syncthreads();

        // 16-way readback (contiguous 128B, broadcast) + strict-> tree merge
        // (prefers lower wave on ties; keys embed index so ties are benign)
        u64 kk[16];
#pragma unroll
        for (int w = 0; w < 16; ++w) kk[w] = s_ck[buf][w];
#pragma unroll
        for (int st = 8; st >= 1; st >>= 1)
#pragma unroll
            for (int j = 0; j < st; ++j)
                if (kk[j+st] > kk[j]) kk[j] = kk[j+st];
        far = (int)~((unsigned)kk[0]);
        float4 c = s_xyz[far];
        cx = c.x; cy = c.y; cz = c.z;
    }
}

// ---------------------------------------------------------------------------
// kNN with tournament caching (verified): per-thread local min cached in a
// register; per pass only cached minima are DPP-reduced; the winning thread
// clears its key and rescans its 16. Bit-exact vs reference.
// ---------------------------------------------------------------------------
__global__ __launch_bounds__(256) void knn_kernel(const float* __restrict__ xyz,
                                                  const int* __restrict__ fps_idx,
                                                  int* __restrict__ nbr_idx)
{
    const int bs = blockIdx.x;
    const int b  = bs >> 10;
    const int t  = threadIdx.x;
    const float* xb = xyz + (size_t)b * NPTS * 3;
    const int ci = fps_idx[bs];
    const float cx = xb[ci*3], cy = xb[ci*3+1], cz = xb[ci*3+2];
    const float sqc = __fadd_rn(__fadd_rn(__fmul_rn(cx,cx), __fmul_rn(cy,cy)), __fmul_rn(cz,cz));

    u64 key[16];
#pragma unroll
    for (int i = 0; i < 16; ++i) {
        int p = t + i * 256;
        float x = xb[p*3], y = xb[p*3+1], z = xb[p*3+2];
        float sqm = __fadd_rn(__fadd_rn(__fmul_rn(x,x), __fmul_rn(y,y)), __fmul_rn(z,z));
        float dot = __fadd_rn(__fadd_rn(__fmul_rn(cx,x), __fmul_rn(cy,y)), __fmul_rn(cz,z));
        float dv  = __fsub_rn(__fadd_rn(sqc, sqm), __fmul_rn(2.0f, dot));
        unsigned u = __float_as_uint(dv);
        u ^= (unsigned)(((int)u >> 31)) | 0x80000000u;   // order-monotonic for all floats
        key[i] = ((u64)u << 32) | (unsigned)p;
    }
    u64 kmin = key[0];
#pragma unroll
    for (int i = 1; i < 16; ++i) if (key[i] < kmin) kmin = key[i];

    __shared__ u64 s_ck[2][4];

    for (int kk = 0; kk < KNN; ++kk) {
        u64 k = wave_red_u64<false>(kmin);
        const int buf = kk & 1;
        if ((t & 63) == 63) s_ck[buf][t>>6] = k;
        __syncthreads();
        u64 k0 = s_ck[buf][0], k1 = s_ck[buf][1], k2 = s_ck[buf][2], k3 = s_ck[buf][3];
        if (k1 < k0) k0 = k1;
        if (k3 < k2) k2 = k3;
        if (k2 < k0) k0 = k2;
        unsigned w = (unsigned)k0;
        if (t == 0) nbr_idx[bs*KNN + kk] = (int)w;
        if ((w & 255u) == (unsigned)t) {          // only the owner thread
#pragma unroll
            for (int i = 0; i < 16; ++i)
                if (w == (unsigned)(t + i*256)) key[i] = ~0ull;
            u64 m = key[0];
#pragma unroll
            for (int i = 1; i < 16; ++i) if (key[i] < m) m = key[i];
            kmin = m;
        }
    }
}

// ---------------------------------------------------------------------------
// Attention with precomputed M = Wq·Wk^T and padded Wvp. Wave g owns center
// g: staging, u = cf·M, scores, softmax, wfea are all wave-private; only the
// o-phase (o = wf·Wvp, coalesced on h=t) crosses waves. All LDS reads f4.
// ---------------------------------------------------------------------------
template<int TYPE>
__device__ __forceinline__ void attn_t(
    int b, int bs0, int ci,
    const float* __restrict__ fea, const float* __restrict__ aux,
    const float* __restrict__ Mt, const float* __restrict__ Wvpt,
    float* __restrict__ outp,
    float (*s_cf)[CIN], float (*s_u)[DP], float (*s_fea)[KNN][DP],
    float (*s_sc)[KNN], float (*s_wf)[DP], const int (*s_nbr4)[KNN])
{
    const int t = threadIdx.x, g = t >> 6, l = t & 63;
    const int l31 = l & 31, h32 = l >> 5;

    // ---- stage (wave-private to center g) ----
    if (l < 32) {
        float4 v = *(const float4*)&fea[((size_t)(b*NPTS + ci))*CIN + l*4];
        *(float4*)&s_cf[g][l*4] = v;
    }
#pragma unroll
    for (int it = 0; it < 16; ++it) {
        int kk = it*2 + h32;
        int j  = s_nbr4[g][kk];
        float4 v = *(const float4*)&fea[((size_t)(b*NPTS + j))*CIN + l31*4];
        *(float4*)&s_fea[g][kk][l31*4] = v;
    }
    if (l < KNN) {
        int j = s_nbr4[g][l];
        float pad[8];
        if (TYPE == 0 || TYPE == 3) {
#pragma unroll
            for (int i = 0; i < 3; ++i)
                pad[i] = aux[(size_t)(b*NPTS + j)*3 + i] - aux[(size_t)(b*NPTS + ci)*3 + i];
            pad[3]=pad[4]=pad[5]=pad[6]=pad[7]=0.f;
        } else if (TYPE == 1) {
            pad[0] = aux[(size_t)(b*NPTS + j)*2 + 0];
            pad[1] = aux[(size_t)(b*NPTS + j)*2 + 1];
            pad[2] = aux[(size_t)(b*NPTS + ci)*2 + 0];
            pad[3] = aux[(size_t)(b*NPTS + ci)*2 + 1];
            pad[4]=pad[5]=pad[6]=pad[7]=0.f;
        } else {
#pragma unroll
            for (int i = 0; i < 4; ++i) pad[i]   = aux[(size_t)(b*NPTS + j)*4 + i];
#pragma unroll
            for (int i = 0; i < 4; ++i) pad[4+i] = aux[(size_t)(b*NPTS + ci)*4 + i];
        }
#pragma unroll
        for (int i = 0; i < 8; ++i) s_fea[g][l][CIN+i] = pad[i];
    }
    __syncthreads();

    // ---- u[g][d] = sum_c cf[g][c] * M[c][d]  (M coalesced, cf via b128) ----
#pragma unroll
    for (int j = 0; j < 3; ++j) {
        int d = l + 64*j;
        if (d < DP) {
            float acc = 0.f;
            for (int c = 0; c < CIN; c += 4) {
                float4 cf4 = *(const float4*)&s_cf[g][c];
                acc = fmaf(cf4.x, Mt[(size_t)(c+0)*DP + d], acc);
                acc = fmaf(cf4.y, Mt[(size_t)(c+1)*DP + d], acc);
                acc = fmaf(cf4.z, Mt[(size_t)(c+2)*DP + d], acc);
                acc = fmaf(cf4.w, Mt[(size_t)(c+3)*DP + d], acc);
            }
            s_u[g][d] = acc;
        }
    }
    __syncthreads();

    // ---- scores[g][kk] = (u[g] . fea[g][kk]) / 16  (two dots per wave) ----
#pragma unroll
    for (int it = 0; it < 16; ++it) {
        int kk = it*2 + h32;
        float acc = 0.f;
        for (int c = l31; c < DP/4; c += 32) {
            float4 f4 = *(const float4*)&s_fea[g][kk][c*4];
            float4 u4 = *(const float4*)&s_u[g][c*4];
            acc = fmaf(f4.x,u4.x,acc); acc = fmaf(f4.y,u4.y,acc);
            acc = fmaf(f4.z,u4.z,acc); acc = fmaf(f4.w,u4.w,acc);
        }
#pragma unroll
        for (int off = 16; off; off >>= 1) acc += __shfl_xor(acc, off);
        if (l31 == 0) s_sc[g][kk] = acc * 0.0625f;
    }
    __syncthreads();

    // ---- softmax over 32 (lanes 0..31 of wave g) ----
    if (l < KNN) {
        float sc = s_sc[g][l];
        float m = sc;
#pragma unroll
        for (int off = 16; off; off >>= 1) m = fmaxf(m, __shfl_xor(m, off));
        float e = expf(sc - m);
        float ssum = e;
#pragma unroll
        for (int off = 16; off; off >>= 1) ssum += __shfl_xor(ssum, off);
        s_sc[g][l] = e / ssum;
    }
    __syncthreads();

    // ---- wfea[g][d] = sum_k attn[g][k] * fea[g][k][d]  (f4 chunks) ----
    if (l < DP/4) {
        const int d0 = l*4;
        float w0=0.f, w1=0.f, w2=0.f, w3=0.f;
#pragma unroll
        for (int k4 = 0; k4 < KNN; k4 += 4) {
            float4 a  = *(const float4*)&s_sc[g][k4];
            float4 f0 = *(const float4*)&s_fea[g][k4+0][d0];
            float4 f1 = *(const float4*)&s_fea[g][k4+1][d0];
            float4 f2 = *(const float4*)&s_fea[g][k4+2][d0];
            float4 f3 = *(const float4*)&s_fea[g][k4+3][d0];
            w0=fmaf(a.x,f0.x,w0); w1=fmaf(a.x,f0.y,w1); w2=fmaf(a.x,f0.z,w2); w3=fmaf(a.x,f0.w,w3);
            w0=fmaf(a.y,f1.x,w0); w1=fmaf(a.y,f1.y,w1); w2=fmaf(a.y,f1.z,w2); w3=fmaf(a.y,f1.w,w3);
            w0=fmaf(a.z,f2.x,w0); w1=fmaf(a.z,f2.y,w1); w2=fmaf(a.z,f2.z,w2); w3=fmaf(a.z,f2.w,w3);
            w0=fmaf(a.w,f3.x,w0); w1=fmaf(a.w,f3.y,w1); w2=fmaf(a.w,f3.z,w2); w3=fmaf(a.w,f3.w,w3);
        }
        s_wf[g][d0+0]=w0; s_wf[g][d0+1]=w1; s_wf[g][d0+2]=w2; s_wf[g][d0+3]=w3;
    }
    __syncthreads();

    // ---- o[g][h=t] = sum_d wf[g][d] * Wvp[d][h]  (cross-wave, coalesced) ----
    float o0=0.f, o1=0.f, o2=0.f, o3=0.f;
    for (int d4 = 0; d4 < DP/4; ++d4) {
        float4 wf0 = *(const float4*)&s_wf[0][d4*4];
        float4 wf1 = *(const float4*)&s_wf[1][d4*4];
        float4 wf2 = *(const float4*)&s_wf[2][d4*4];
        float4 wf3 = *(const float4*)&s_wf[3][d4*4];
        float v0 = Wvpt[(size_t)(d4*4+0)*CO + t];
        float v1 = Wvpt[(size_t)(d4*4+1)*CO + t];
        float v2 = Wvpt[(size_t)(d4*4+2)*CO + t];
        float v3 = Wvpt[(size_t)(d4*4+3)*CO + t];
        o0=fmaf(wf0.x,v0,o0); o0=fmaf(wf0.y,v1,o0); o0=fmaf(wf0.z,v2,o0); o0=fmaf(wf0.w,v3,o0);
        o1=fmaf(wf1.x,v0,o1); o1=fmaf(wf1.y,v1,o1); o1=fmaf(wf1.z,v2,o1); o1=fmaf(wf1.w,v3,o1);
        o2=fmaf(wf2.x,v0,o2); o2=fmaf(wf2.y,v1,o2); o2=fmaf(wf2.z,v2,o2); o2=fmaf(wf2.w,v3,o2);
        o3=fmaf(wf3.x,v0,o3); o3=fmaf(wf3.y,v1,o3); o3=fmaf(wf3.z,v2,o3); o3=fmaf(wf3.w,v3,o3);
    }
    outp[(size_t)(bs0+0)*CO + t] = o0;
    outp[(size_t)(bs0+1)*CO + t] = o1;
    outp[(size_t)(bs0+2)*CO + t] = o2;
    outp[(size_t)(bs0+3)*CO + t] = o3;
    __syncthreads();
}

__global__ __launch_bounds__(256) void attn_kernel(
    const float* __restrict__ xyz, const float* __restrict__ mad,
    const float* __restrict__ adj, const float* __restrict__ pt,
    const float* __restrict__ mad_fea, const float* __restrict__ adj_fea,
    const float* __restrict__ pt_fea,  const float* __restrict__ cst_fea,
    const float* __restrict__ M, const float* __restrict__ Wvp,
    const int* __restrict__ fps_idx, const int* __restrict__ nbr_idx,
    float* __restrict__ out)
{
    __shared__ float s_cf[4][CIN];
    __shared__ float s_u[4][DP];
    __shared__ float s_fea[4][KNN][DP];
    __shared__ float s_sc[4][KNN];
    __shared__ float s_wf[4][DP];
    __shared__ int   s_nbr4[4][KNN];
    __shared__ int   s_ci4[4];

    const int bs0 = blockIdx.x * 4;
    const int b   = bs0 >> 10;
    const int t   = threadIdx.x;
    const int g   = t >> 6, l = t & 63;

    if (t < 4) s_ci4[t] = fps_idx[bs0 + t];
    if (t < 128) s_nbr4[t>>5][t&31] = nbr_idx[(bs0 + (t>>5))*KNN + (t&31)];
    __syncthreads();
    const int ci = s_ci4[g];

    // small per-center outputs (wave-private)
    if (l < 3)             out[OFF_CXYZ + (bs0+g)*3 + l]      = xyz[(size_t)(b*NPTS+ci)*3 + l];
    if (l >= 4 && l < 7)   out[OFF_CMAD + (bs0+g)*3 + (l-4)]  = mad[(size_t)(b*NPTS+ci)*3 + (l-4)];
    if (l >= 8 && l < 10)  out[OFF_CADJ + (bs0+g)*2 + (l-8)]  = adj[(size_t)(b*NPTS+ci)*2 + (l-8)];
    if (l >= 12 && l < 16) out[OFF_CPT  + (bs0+g)*4 + (l-12)] = pt[(size_t)(b*NPTS+ci)*4 + (l-12)];

    attn_t<0>(b, bs0, ci, mad_fea, mad, M + 0*CIN*DP, Wvp + 0*DP*CO, out + OFF_OMAD,
              s_cf, s_u, s_fea, s_sc, s_wf, s_nbr4);
    attn_t<1>(b, bs0, ci, adj_fea, adj, M + 1*CIN*DP, Wvp + 1*DP*CO, out + OFF_OADJ,
              s_cf, s_u, s_fea, s_sc, s_wf, s_nbr4);
    attn_t<2>(b, bs0, ci, pt_fea,  pt,  M + 2*CIN*DP, Wvp + 2*DP*CO, out + OFF_OPT,
              s_cf, s_u, s_fea, s_sc, s_wf, s_nbr4);
    attn_t<3>(b, bs0, ci, cst_fea, xyz, M + 3*CIN*DP, Wvp + 3*DP*CO, out + OFF_OCST,
              s_cf, s_u, s_fea, s_sc, s_wf, s_nbr4);
}

extern "C" void kernel_launch(void* const* d_in, const int* in_sizes, int n_in,
                              void* d_out, int out_size, void* d_ws, size_t ws_size,
                              hipStream_t stream)
{
    const float* xyz     = (const float*)d_in[0];
    const float* mad     = (const float*)d_in[1];
    const float* adj     = (const float*)d_in[2];
    const float* pt      = (const float*)d_in[3];
    const float* mad_fea = (const float*)d_in[4];
    const float* adj_fea = (const float*)d_in[5];
    const float* pt_fea  = (const float*)d_in[6];
    const float* cst_fea = (const float*)d_in[7];
    const float* wq_mad  = (const float*)d_in[8];
    const float* wk_mad  = (const float*)d_in[9];
    const float* wv_mad  = (const float*)d_in[10];
    const float* wq_adj  = (const float*)d_in[11];
    const float* wk_adj  = (const float*)d_in[12];
    const float* wv_adj  = (const float*)d_in[13];
    const float* wq_pt   = (const float*)d_in[14];
    const float* wk_pt   = (const float*)d_in[15];
    const float* wv_pt   = (const float*)d_in[16];
    const float* wq_cst  = (const float*)d_in[17];
    const float* wk_cst  = (const float*)d_in[18];
    const float* wv_cst  = (const float*)d_in[19];
    float* out = (float*)d_out;

    int*   fps_idx = (int*)d_ws;                      // 4096 ints
    int*   nbr_idx = fps_idx + BATCH*NC;              // 131072 ints
    float* M       = (float*)(nbr_idx + BATCH*NC*KNN);// 4*128*136 floats
    float* Wvp     = M + 4*CIN*DP;                    // 4*136*256 floats

    fps_prep_kernel<<<BATCH + 4*DP, 1024, 0, stream>>>(xyz, fps_idx,
        wq_mad, wk_mad, wv_mad, wq_adj, wk_adj, wv_adj,
        wq_pt, wk_pt, wv_pt, wq_cst, wk_cst, wv_cst, M, Wvp);
    knn_kernel<<<BATCH*NC, 256, 0, stream>>>(xyz, fps_idx, nbr_idx);
    attn_kernel<<<BATCH*NC/4, 256, 0, stream>>>(xyz, mad, adj, pt,
        mad_fea, adj_fea, pt_fea, cst_fea, M, Wvp, fps_idx, nbr_idx, out);
}

// Round 5
// 1116.955 us; speedup vs baseline: 1.4666x; 1.3171x over previous
//
#include <hip/hip_runtime.h>

#define BATCH 4
#define NPTS  4096
#define NC    1024
#define KNN   32
#define CIN   128
#define CO    256
#define DP    136   // padded feature dim (max over types); pad entries are exact zeros

// output layout (flat f32, reference return order)
#define OFF_CXYZ 0
#define OFF_CMAD (BATCH*NC*3)
#define OFF_CADJ (OFF_CMAD + BATCH*NC*3)
#define OFF_CPT  (OFF_CADJ + BATCH*NC*2)
#define OFF_OMAD (OFF_CPT  + BATCH*NC*4)
#define OFF_OADJ (OFF_OMAD + BATCH*NC*CO)
#define OFF_OPT  (OFF_OADJ + BATCH*NC*CO)
#define OFF_OCST (OFF_OPT  + BATCH*NC*CO)

typedef unsigned long long u64;

// ---------------------------------------------------------------------------
// u64 wave-64 reduce via DPP (VALU pipe). Result valid in lane 63.
// ---------------------------------------------------------------------------
template<bool MAXI>
__device__ __forceinline__ u64 wave_red_u64(u64 k)
{
    const int oldv = MAXI ? 0 : -1;
#define DPP_STEP(C)                                                              \
    {                                                                            \
        unsigned plo = (unsigned)__builtin_amdgcn_update_dpp(oldv, (int)(unsigned)k,        C, 0xf, 0xf, false); \
        unsigned phi = (unsigned)__builtin_amdgcn_update_dpp(oldv, (int)(unsigned)(k>>32),  C, 0xf, 0xf, false); \
        u64 p = ((u64)phi << 32) | plo;                                          \
        if (MAXI ? (p > k) : (p < k)) k = p;                                     \
    }
    DPP_STEP(0x111) DPP_STEP(0x112) DPP_STEP(0x114)
    DPP_STEP(0x118) DPP_STEP(0x142) DPP_STEP(0x143)
#undef DPP_STEP
    return k;
}

// ---------------------------------------------------------------------------
// Fused kernel: blocks 0..3 run FPS; blocks 4..547 precompute M[type] =
// Wq·Wk^T (zero-padded to 136) and the zero-padded Wvp.
//
// KEY FIX vs the 658us version: the per-step winner index is buffered in LDS
// (s_far) instead of being stored to global inside the barrier loop.
// __syncthreads() compiles to s_waitcnt vmcnt(0) lgkmcnt(0) + s_barrier, so
// a global store in the loop forced a ~200-500cy store-retire drain onto the
// critical path of every one of the 1024 serial steps. The ds_write drains
// with the lgkmcnt(0) that the s_ck write already requires (~free). The 1024
// indices are dumped to global once, coalesced, after the loop.
// ---------------------------------------------------------------------------
__global__ __launch_bounds__(256) void fps_prep_kernel(
    const float* __restrict__ xyz, int* __restrict__ fps_idx,
    const float* __restrict__ wq_mad, const float* __restrict__ wk_mad, const float* __restrict__ wv_mad,
    const float* __restrict__ wq_adj, const float* __restrict__ wk_adj, const float* __restrict__ wv_adj,
    const float* __restrict__ wq_pt,  const float* __restrict__ wk_pt,  const float* __restrict__ wv_pt,
    const float* __restrict__ wq_cst, const float* __restrict__ wk_cst, const float* __restrict__ wv_cst,
    float* __restrict__ M, float* __restrict__ Wvp)
{
    __shared__ float4 s_xyz[NPTS];          // 64 KB (prep reuses as scratch)
    __shared__ u64    s_ck[2][4];
    __shared__ int    s_far[NC];            // 4 KB winner buffer
    const int t = threadIdx.x;

    if (blockIdx.x >= BATCH) {
        // ---------------- prep path ----------------
        const int r    = blockIdx.x - BATCH;   // 0..4*DP-1
        const int type = r / DP;
        const int row  = r - type * DP;
        const float* wq; const float* wk; const float* wv; int D;
        if (type == 0)      { wq=wq_mad; wk=wk_mad; wv=wv_mad; D=131; }
        else if (type == 1) { wq=wq_adj; wk=wk_adj; wv=wv_adj; D=132; }
        else if (type == 2) { wq=wq_pt;  wk=wk_pt;  wv=wv_pt;  D=136; }
        else                { wq=wq_cst; wk=wk_cst; wv=wv_cst; D=131; }

        // zero-padded Wvp row
        Wvp[((size_t)type*DP + row)*CO + t] = (row < D) ? wv[(size_t)row*CO + t] : 0.f;

        // M[row][d] = sum_h Wq[row][h] * Wk[d][h]   (zero for d >= D)
        if (row < CIN) {
            float* sq = (float*)s_xyz;
            sq[t] = wq[(size_t)row*CO + t];
            __syncthreads();
            if (t < DP) {
                float acc = 0.f;
                if (t < D) {
                    const float* wkr = wk + (size_t)t * CO;
                    for (int h = 0; h < CO; h += 4) {
                        float4 a = *(const float4*)&wkr[h];
                        float4 b4 = *(const float4*)&sq[h];
                        acc = fmaf(a.x,b4.x,acc); acc = fmaf(a.y,b4.y,acc);
                        acc = fmaf(a.z,b4.z,acc); acc = fmaf(a.w,b4.w,acc);
                    }
                }
                M[((size_t)type*CIN + row)*DP + t] = acc;
            }
        }
        return;
    }

    // ---------------- FPS path (verified round-2 math) ----------------
    const int b = blockIdx.x;
    const float* xb = xyz + (size_t)b * NPTS * 3;

    float px[16], py[16], pz[16], dd[16];
#pragma unroll
    for (int i = 0; i < 16; ++i) {
        int p = t + i * 256;
        px[i] = xb[p*3+0]; py[i] = xb[p*3+1]; pz[i] = xb[p*3+2];
        s_xyz[p] = make_float4(px[i], py[i], pz[i], 0.f);
        dd[i] = 1e10f;
    }
    __syncthreads();

    int far = 0;
    float cx = xb[0], cy = xb[1], cz = xb[2];
    for (int s = 0; s < NC; ++s) {
        if (t == 0) s_far[s] = far;           // LDS, not global: no vmcnt drain

        // 4 independent running-max chains (groups of 4 points).
        // Strict > keeps the EARLIEST i in a group -> smallest point index.
        float    gm[4] = {-1.f, -1.f, -1.f, -1.f};
        unsigned gi[4] = {0u, 0u, 0u, 0u};
#pragma unroll
        for (int i = 0; i < 16; ++i) {
            float dx = __fsub_rn(px[i], cx);
            float dy = __fsub_rn(py[i], cy);
            float dz = __fsub_rn(pz[i], cz);
            float d  = __fadd_rn(__fadd_rn(__fmul_rn(dx,dx), __fmul_rn(dy,dy)), __fmul_rn(dz,dz));
            float nd = fminf(dd[i], d);
            dd[i] = nd;
            const int g = i >> 2;
            if (nd > gm[g]) gi[g] = (unsigned)(t + i*256);
            gm[g] = fmaxf(gm[g], nd);
        }
        // group merges: strict > prefers the lower group (smaller indices)
        bool c1 = gm[1] > gm[0]; float a0 = c1 ? gm[1] : gm[0]; unsigned b0 = c1 ? gi[1] : gi[0];
        bool c3 = gm[3] > gm[2]; float a1 = c3 ? gm[3] : gm[2]; unsigned b1 = c3 ? gi[3] : gi[2];
        bool cf = a1 > a0;       float am = cf ? a1 : a0;       unsigned bm = cf ? b1 : b0;
        // same key as the verified u64 tournament: (dist_bits<<32) | ~idx
        u64 k = ((u64)__float_as_uint(am) << 32) | (u64)(unsigned)~bm;

        k = wave_red_u64<true>(k);

        const int buf = s & 1;
        if ((t & 63) == 63) s_ck[buf][t>>6] = k;
        __syncthreads();
        u64 k0 = s_ck[buf][0], k1 = s_ck[buf][1], k2 = s_ck[buf][2], k3 = s_ck[buf][3];
        // speculative coord fetch for all 4 wave winners (broadcast reads),
        // overlapped with the key merge; winner selected by cndmask.
        float4 c0 = s_xyz[(int)~((unsigned)k0)];
        float4 c1v = s_xyz[(int)~((unsigned)k1)];
        float4 c2v = s_xyz[(int)~((unsigned)k2)];
        float4 c3v = s_xyz[(int)~((unsigned)k3)];
        bool m1 = k1 > k0; u64 ka = m1 ? k1 : k0; float4 ca = m1 ? c1v : c0;
        bool m3 = k3 > k2; u64 kb = m3 ? k3 : k2; float4 cb = m3 ? c3v : c2v;
        bool mf = kb > ka; u64 kw = mf ? kb : ka; float4 cw = mf ? cb : ca;
        far = (int)~((unsigned)kw);
        cx = cw.x; cy = cw.y; cz = cw.z;
    }

    // coalesced write-out of all 1024 indices (once, outside the loop)
    __syncthreads();
#pragma unroll
    for (int j = 0; j < 4; ++j)
        fps_idx[b*NC + t + j*256] = s_far[t + j*256];
}

// ---------------------------------------------------------------------------
// kNN with tournament caching (verified). KEY FIX: the per-iteration winner w
// is known to ALL threads after the merge, so thread kk keeps iteration kk's
// winner in a register and the 32 results are stored once after the loop --
// no global store (and no vmcnt drain at the barrier) inside the loop.
// ---------------------------------------------------------------------------
__global__ __launch_bounds__(256) void knn_kernel(const float* __restrict__ xyz,
                                                  const int* __restrict__ fps_idx,
                                                  int* __restrict__ nbr_idx)
{
    const int bs = blockIdx.x;
    const int b  = bs >> 10;
    const int t  = threadIdx.x;
    const float* xb = xyz + (size_t)b * NPTS * 3;
    const int ci = fps_idx[bs];
    const float cx = xb[ci*3], cy = xb[ci*3+1], cz = xb[ci*3+2];
    const float sqc = __fadd_rn(__fadd_rn(__fmul_rn(cx,cx), __fmul_rn(cy,cy)), __fmul_rn(cz,cz));

    u64 key[16];
#pragma unroll
    for (int i = 0; i < 16; ++i) {
        int p = t + i * 256;
        float x = xb[p*3], y = xb[p*3+1], z = xb[p*3+2];
        float sqm = __fadd_rn(__fadd_rn(__fmul_rn(x,x), __fmul_rn(y,y)), __fmul_rn(z,z));
        float dot = __fadd_rn(__fadd_rn(__fmul_rn(cx,x), __fmul_rn(cy,y)), __fmul_rn(cz,z));
        float dv  = __fsub_rn(__fadd_rn(sqc, sqm), __fmul_rn(2.0f, dot));
        unsigned u = __float_as_uint(dv);
        u ^= (unsigned)(((int)u >> 31)) | 0x80000000u;   // order-monotonic for all floats
        key[i] = ((u64)u << 32) | (unsigned)p;
    }
    u64 kmin = key[0];
#pragma unroll
    for (int i = 1; i < 16; ++i) if (key[i] < kmin) kmin = key[i];

    __shared__ u64 s_ck[2][4];

    int myw = 0;                              // thread t holds winner of iter t (t<32)

    for (int kk = 0; kk < KNN; ++kk) {
        u64 k = wave_red_u64<false>(kmin);
        const int buf = kk & 1;
        if ((t & 63) == 63) s_ck[buf][t>>6] = k;
        __syncthreads();
        u64 k0 = s_ck[buf][0], k1 = s_ck[buf][1], k2 = s_ck[buf][2], k3 = s_ck[buf][3];
        if (k1 < k0) k0 = k1;
        if (k3 < k2) k2 = k3;
        if (k2 < k0) k0 = k2;
        unsigned w = (unsigned)k0;
        if (kk == t) myw = (int)w;            // register, no store in loop
        if ((w & 255u) == (unsigned)t) {      // only the owner thread
#pragma unroll
            for (int i = 0; i < 16; ++i)
                if (w == (unsigned)(t + i*256)) key[i] = ~0ull;
            u64 m = key[0];
#pragma unroll
            for (int i = 1; i < 16; ++i) if (key[i] < m) m = key[i];
            kmin = m;
        }
    }
    if (t < KNN) nbr_idx[bs*KNN + t] = myw;
}

// ---------------------------------------------------------------------------
// Attention with precomputed M = Wq·Wk^T and padded Wvp. Wave g owns center
// g: staging, u = cf·M, scores, softmax, wfea are all wave-private; only the
// o-phase (o = wf·Wvp, coalesced on h=t) crosses waves. All LDS reads f4.
// ---------------------------------------------------------------------------
template<int TYPE>
__device__ __forceinline__ void attn_t(
    int b, int bs0, int ci,
    const float* __restrict__ fea, const float* __restrict__ aux,
    const float* __restrict__ Mt, const float* __restrict__ Wvpt,
    float* __restrict__ outp,
    float (*s_cf)[CIN], float (*s_u)[DP], float (*s_fea)[KNN][DP],
    float (*s_sc)[KNN], float (*s_wf)[DP], const int (*s_nbr4)[KNN])
{
    const int t = threadIdx.x, g = t >> 6, l = t & 63;
    const int l31 = l & 31, h32 = l >> 5;

    // ---- stage (wave-private to center g) ----
    if (l < 32) {
        float4 v = *(const float4*)&fea[((size_t)(b*NPTS + ci))*CIN + l*4];
        *(float4*)&s_cf[g][l*4] = v;
    }
#pragma unroll
    for (int it = 0; it < 16; ++it) {
        int kk = it*2 + h32;
        int j  = s_nbr4[g][kk];
        float4 v = *(const float4*)&fea[((size_t)(b*NPTS + j))*CIN + l31*4];
        *(float4*)&s_fea[g][kk][l31*4] = v;
    }
    if (l < KNN) {
        int j = s_nbr4[g][l];
        float pad[8];
        if (TYPE == 0 || TYPE == 3) {
#pragma unroll
            for (int i = 0; i < 3; ++i)
                pad[i] = aux[(size_t)(b*NPTS + j)*3 + i] - aux[(size_t)(b*NPTS + ci)*3 + i];
            pad[3]=pad[4]=pad[5]=pad[6]=pad[7]=0.f;
        } else if (TYPE == 1) {
            pad[0] = aux[(size_t)(b*NPTS + j)*2 + 0];
            pad[1] = aux[(size_t)(b*NPTS + j)*2 + 1];
            pad[2] = aux[(size_t)(b*NPTS + ci)*2 + 0];
            pad[3] = aux[(size_t)(b*NPTS + ci)*2 + 1];
            pad[4]=pad[5]=pad[6]=pad[7]=0.f;
        } else {
#pragma unroll
            for (int i = 0; i < 4; ++i) pad[i]   = aux[(size_t)(b*NPTS + j)*4 + i];
#pragma unroll
            for (int i = 0; i < 4; ++i) pad[4+i] = aux[(size_t)(b*NPTS + ci)*4 + i];
        }
#pragma unroll
        for (int i = 0; i < 8; ++i) s_fea[g][l][CIN+i] = pad[i];
    }
    __syncthreads();

    // ---- u[g][d] = sum_c cf[g][c] * M[c][d]  (M coalesced, cf via b128) ----
#pragma unroll
    for (int j = 0; j < 3; ++j) {
        int d = l + 64*j;
        if (d < DP) {
            float acc = 0.f;
            for (int c = 0; c < CIN; c += 4) {
                float4 cf4 = *(const float4*)&s_cf[g][c];
                acc = fmaf(cf4.x, Mt[(size_t)(c+0)*DP + d], acc);
                acc = fmaf(cf4.y, Mt[(size_t)(c+1)*DP + d], acc);
                acc = fmaf(cf4.z, Mt[(size_t)(c+2)*DP + d], acc);
                acc = fmaf(cf4.w, Mt[(size_t)(c+3)*DP + d], acc);
            }
            s_u[g][d] = acc;
        }
    }
    __syncthreads();

    // ---- scores[g][kk] = (u[g] . fea[g][kk]) / 16  (two dots per wave) ----
#pragma unroll
    for (int it = 0; it < 16; ++it) {
        int kk = it*2 + h32;
        float acc = 0.f;
        for (int c = l31; c < DP/4; c += 32) {
            float4 f4 = *(const float4*)&s_fea[g][kk][c*4];
            float4 u4 = *(const float4*)&s_u[g][c*4];
            acc = fmaf(f4.x,u4.x,acc); acc = fmaf(f4.y,u4.y,acc);
            acc = fmaf(f4.z,u4.z,acc); acc = fmaf(f4.w,u4.w,acc);
        }
#pragma unroll
        for (int off = 16; off; off >>= 1) acc += __shfl_xor(acc, off);
        if (l31 == 0) s_sc[g][kk] = acc * 0.0625f;
    }
    __syncthreads();

    // ---- softmax over 32 (lanes 0..31 of wave g) ----
    if (l < KNN) {
        float sc = s_sc[g][l];
        float m = sc;
#pragma unroll
        for (int off = 16; off; off >>= 1) m = fmaxf(m, __shfl_xor(m, off));
        float e = expf(sc - m);
        float ssum = e;
#pragma unroll
        for (int off = 16; off; off >>= 1) ssum += __shfl_xor(ssum, off);
        s_sc[g][l] = e / ssum;
    }
    __syncthreads();

    // ---- wfea[g][d] = sum_k attn[g][k] * fea[g][k][d]  (f4 chunks) ----
    if (l < DP/4) {
        const int d0 = l*4;
        float w0=0.f, w1=0.f, w2=0.f, w3=0.f;
#pragma unroll
        for (int k4 = 0; k4 < KNN; k4 += 4) {
            float4 a  = *(const float4*)&s_sc[g][k4];
            float4 f0 = *(const float4*)&s_fea[g][k4+0][d0];
            float4 f1 = *(const float4*)&s_fea[g][k4+1][d0];
            float4 f2 = *(const float4*)&s_fea[g][k4+2][d0];
            float4 f3 = *(const float4*)&s_fea[g][k4+3][d0];
            w0=fmaf(a.x,f0.x,w0); w1=fmaf(a.x,f0.y,w1); w2=fmaf(a.x,f0.z,w2); w3=fmaf(a.x,f0.w,w3);
            w0=fmaf(a.y,f1.x,w0); w1=fmaf(a.y,f1.y,w1); w2=fmaf(a.y,f1.z,w2); w3=fmaf(a.y,f1.w,w3);
            w0=fmaf(a.z,f2.x,w0); w1=fmaf(a.z,f2.y,w1); w2=fmaf(a.z,f2.z,w2); w3=fmaf(a.z,f2.w,w3);
            w0=fmaf(a.w,f3.x,w0); w1=fmaf(a.w,f3.y,w1); w2=fmaf(a.w,f3.z,w2); w3=fmaf(a.w,f3.w,w3);
        }
        s_wf[g][d0+0]=w0; s_wf[g][d0+1]=w1; s_wf[g][d0+2]=w2; s_wf[g][d0+3]=w3;
    }
    __syncthreads();

    // ---- o[g][h=t] = sum_d wf[g][d] * Wvp[d][h]  (cross-wave, coalesced) ----
    float o0=0.f, o1=0.f, o2=0.f, o3=0.f;
    for (int d4 = 0; d4 < DP/4; ++d4) {
        float4 wf0 = *(const float4*)&s_wf[0][d4*4];
        float4 wf1 = *(const float4*)&s_wf[1][d4*4];
        float4 wf2 = *(const float4*)&s_wf[2][d4*4];
        float4 wf3 = *(const float4*)&s_wf[3][d4*4];
        float v0 = Wvpt[(size_t)(d4*4+0)*CO + t];
        float v1 = Wvpt[(size_t)(d4*4+1)*CO + t];
        float v2 = Wvpt[(size_t)(d4*4+2)*CO + t];
        float v3 = Wvpt[(size_t)(d4*4+3)*CO + t];
        o0=fmaf(wf0.x,v0,o0); o0=fmaf(wf0.y,v1,o0); o0=fmaf(wf0.z,v2,o0); o0=fmaf(wf0.w,v3,o0);
        o1=fmaf(wf1.x,v0,o1); o1=fmaf(wf1.y,v1,o1); o1=fmaf(wf1.z,v2,o1); o1=fmaf(wf1.w,v3,o1);
        o2=fmaf(wf2.x,v0,o2); o2=fmaf(wf2.y,v1,o2); o2=fmaf(wf2.z,v2,o2); o2=fmaf(wf2.w,v3,o2);
        o3=fmaf(wf3.x,v0,o3); o3=fmaf(wf3.y,v1,o3); o3=fmaf(wf3.z,v2,o3); o3=fmaf(wf3.w,v3,o3);
    }
    outp[(size_t)(bs0+0)*CO + t] = o0;
    outp[(size_t)(bs0+1)*CO + t] = o1;
    outp[(size_t)(bs0+2)*CO + t] = o2;
    outp[(size_t)(bs0+3)*CO + t] = o3;
    __syncthreads();
}

__global__ __launch_bounds__(256) void attn_kernel(
    const float* __restrict__ xyz, const float* __restrict__ mad,
    const float* __restrict__ adj, const float* __restrict__ pt,
    const float* __restrict__ mad_fea, const float* __restrict__ adj_fea,
    const float* __restrict__ pt_fea,  const float* __restrict__ cst_fea,
    const float* __restrict__ M, const float* __restrict__ Wvp,
    const int* __restrict__ fps_idx, const int* __restrict__ nbr_idx,
    float* __restrict__ out)
{
    __shared__ float s_cf[4][CIN];
    __shared__ float s_u[4][DP];
    __shared__ float s_fea[4][KNN][DP];
    __shared__ float s_sc[4][KNN];
    __shared__ float s_wf[4][DP];
    __shared__ int   s_nbr4[4][KNN];
    __shared__ int   s_ci4[4];

    const int bs0 = blockIdx.x * 4;
    const int b   = bs0 >> 10;
    const int t   = threadIdx.x;
    const int g   = t >> 6, l = t & 63;

    if (t < 4) s_ci4[t] = fps_idx[bs0 + t];
    if (t < 128) s_nbr4[t>>5][t&31] = nbr_idx[(bs0 + (t>>5))*KNN + (t&31)];
    __syncthreads();
    const int ci = s_ci4[g];

    // small per-center outputs (wave-private)
    if (l < 3)             out[OFF_CXYZ + (bs0+g)*3 + l]      = xyz[(size_t)(b*NPTS+ci)*3 + l];
    if (l >= 4 && l < 7)   out[OFF_CMAD + (bs0+g)*3 + (l-4)]  = mad[(size_t)(b*NPTS+ci)*3 + (l-4)];
    if (l >= 8 && l < 10)  out[OFF_CADJ + (bs0+g)*2 + (l-8)]  = adj[(size_t)(b*NPTS+ci)*2 + (l-8)];
    if (l >= 12 && l < 16) out[OFF_CPT  + (bs0+g)*4 + (l-12)] = pt[(size_t)(b*NPTS+ci)*4 + (l-12)];

    attn_t<0>(b, bs0, ci, mad_fea, mad, M + 0*CIN*DP, Wvp + 0*DP*CO, out + OFF_OMAD,
              s_cf, s_u, s_fea, s_sc, s_wf, s_nbr4);
    attn_t<1>(b, bs0, ci, adj_fea, adj, M + 1*CIN*DP, Wvp + 1*DP*CO, out + OFF_OADJ,
              s_cf, s_u, s_fea, s_sc, s_wf, s_nbr4);
    attn_t<2>(b, bs0, ci, pt_fea,  pt,  M + 2*CIN*DP, Wvp + 2*DP*CO, out + OFF_OPT,
              s_cf, s_u, s_fea, s_sc, s_wf, s_nbr4);
    attn_t<3>(b, bs0, ci, cst_fea, xyz, M + 3*CIN*DP, Wvp + 3*DP*CO, out + OFF_OCST,
              s_cf, s_u, s_fea, s_sc, s_wf, s_nbr4);
}

extern "C" void kernel_launch(void* const* d_in, const int* in_sizes, int n_in,
                              void* d_out, int out_size, void* d_ws, size_t ws_size,
                              hipStream_t stream)
{
    const float* xyz     = (const float*)d_in[0];
    const float* mad     = (const float*)d_in[1];
    const float* adj     = (const float*)d_in[2];
    const float* pt      = (const float*)d_in[3];
    const float* mad_fea = (const float*)d_in[4];
    const float* adj_fea = (const float*)d_in[5];
    const float* pt_fea  = (const float*)d_in[6];
    const float* cst_fea = (const float*)d_in[7];
    const float* wq_mad  = (const float*)d_in[8];
    const float* wk_mad  = (const float*)d_in[9];
    const float* wv_mad  = (const float*)d_in[10];
    const float* wq_adj  = (const float*)d_in[11];
    const float* wk_adj  = (const float*)d_in[12];
    const float* wv_adj  = (const float*)d_in[13];
    const float* wq_pt   = (const float*)d_in[14];
    const float* wk_pt   = (const float*)d_in[15];
    const float* wv_pt   = (const float*)d_in[16];
    const float* wq_cst  = (const float*)d_in[17];
    const float* wk_cst  = (const float*)d_in[18];
    const float* wv_cst  = (const float*)d_in[19];
    float* out = (float*)d_out;

    int*   fps_idx = (int*)d_ws;                      // 4096 ints
    int*   nbr_idx = fps_idx + BATCH*NC;              // 131072 ints
    float* M       = (float*)(nbr_idx + BATCH*NC*KNN);// 4*128*136 floats
    float* Wvp     = M + 4*CIN*DP;                    // 4*136*256 floats

    fps_prep_kernel<<<BATCH + 4*DP, 256, 0, stream>>>(xyz, fps_idx,
        wq_mad, wk_mad, wv_mad, wq_adj, wk_adj, wv_adj,
        wq_pt, wk_pt, wv_pt, wq_cst, wk_cst, wv_cst, M, Wvp);
    knn_kernel<<<BATCH*NC, 256, 0, stream>>>(xyz, fps_idx, nbr_idx);
    attn_kernel<<<BATCH*NC/4, 256, 0, stream>>>(xyz, mad, adj, pt,
        mad_fea, adj_fea, pt_fea, cst_fea, M, Wvp, fps_idx, nbr_idx, out);
}